// Round 1
// baseline (12371.368 us; speedup 1.0000x reference)
//
#include <hip/hip_runtime.h>
#include <hip/hip_cooperative_groups.h>

namespace cg = cooperative_groups;

#define TC 32          // time steps per chunk
#define NCHUNK 16

typedef __attribute__((ext_vector_type(8))) short short8;
typedef __attribute__((ext_vector_type(4))) float float4_t;
typedef __attribute__((ext_vector_type(4))) unsigned int uint4_t;
typedef __attribute__((ext_vector_type(4))) unsigned short ushort4_t;

__device__ inline unsigned short f2bf(float f) {
  union { float f; unsigned u; } v; v.f = f;
  return (unsigned short)((v.u + 0x7fffu + ((v.u >> 16) & 1u)) >> 16);
}
__device__ inline float bf2f(unsigned short b) {
  union { unsigned u; float f; } v; v.u = ((unsigned)b) << 16;
  return v.f;
}
__device__ inline float sigmoidf_(float x) { return 1.f / (1.f + __expf(-x)); }
__device__ inline float tanhf_(float x) {
  float e = __expf(-2.f * fabsf(x));
  float t = (1.f - e) / (1.f + e);
  return x < 0.f ? -t : t;
}

// ---------------- K0: fp32 -> bf16 convert, two sources concatenated ----------------
__global__ __launch_bounds__(256)
void k_cvt2(const float* __restrict__ a, const float* __restrict__ b,
            unsigned short* __restrict__ o, unsigned halfElems) {
  const size_t i = ((size_t)blockIdx.x * 256 + threadIdx.x) * 8;
  const float* s = (i < (size_t)halfElems) ? (a + i) : (b + (i - halfElems));
  float4_t x = *(const float4_t*)s;
  float4_t y = *(const float4_t*)(s + 4);
  short8 v;
  v[0]=(short)f2bf(x.x); v[1]=(short)f2bf(x.y); v[2]=(short)f2bf(x.z); v[3]=(short)f2bf(x.w);
  v[4]=(short)f2bf(y.x); v[5]=(short)f2bf(y.y); v[6]=(short)f2bf(y.z); v[7]=(short)f2bf(y.w);
  *(short8*)(o + i) = v;
}

// ---------------- K1: embedding gather for one chunk (2 windows x 2048 rows) ----------------
__global__ __launch_bounds__(256)
void k_embed_c(const int* __restrict__ src, const float* __restrict__ emb,
               unsigned short* __restrict__ o, int rowF0, int rowB0) {
  const int wi = blockIdx.x * 4 + (threadIdx.x >> 6);  // 0..4095
  const int lane = threadIdx.x & 63;
  const int half = wi >> 11;
  const int rl = wi & 2047;
  const int row = (half ? rowB0 : rowF0) + rl;
  const int tok = src[row];
  short8 v;
  if (tok == 0) {
    v = (short8){0,0,0,0,0,0,0,0};
  } else {
    const float* ep = emb + (size_t)tok * 512 + lane * 8;
    float4_t a = *(const float4_t*)(ep);
    float4_t b = *(const float4_t*)(ep + 4);
    v[0]=(short)f2bf(a.x); v[1]=(short)f2bf(a.y); v[2]=(short)f2bf(a.z); v[3]=(short)f2bf(a.w);
    v[4]=(short)f2bf(b.x); v[5]=(short)f2bf(b.y); v[6]=(short)f2bf(b.z); v[7]=(short)f2bf(b.w);
  }
  *(short8*)(o + ((size_t)half * 2048 + rl) * 512 + lane * 8) = v;
}

// ---------------- K2: chunk x_proj GEMM: [2048,512] x [4096,512]^T per half ----------------
// xp layout per half: 16x16 tiles, tile (mt,nt) at (mt*256+nt)*256, elem order lane*4+reg
__global__ __launch_bounds__(256, 2)
void k_xproj(const unsigned short* __restrict__ Aall,   // embed_c [2][2048][512]
             const unsigned short* __restrict__ Ball,   // wih_b   [8192][512]
             const float* __restrict__ bih_f, const float* __restrict__ bhh_f,
             const float* __restrict__ bih_b, const float* __restrict__ bhh_b,
             unsigned short* __restrict__ xp) {
  __shared__ __align__(16) unsigned short lA[128 * 64];
  __shared__ __align__(16) unsigned short lB[128 * 64];
  const int tid = threadIdx.x;
  const int lane = tid & 63;
  const int w = tid >> 6;
  const int mq = w & 1, nq = w >> 1;
  const int half = blockIdx.x >> 9;      // 0 = fwd gates, 1 = bwd gates
  const int idx = blockIdx.x & 511;
  const int bm = idx & 15;               // 16 M-blocks (2048 rows)
  const int bn = idx >> 4;               // 32 N-blocks (4096 cols)
  const unsigned short* A  = Aall + (size_t)half * 1048576;
  const unsigned short* Bw = Ball + (size_t)half * 2097152;

  float4_t acc[4][4];
#pragma unroll
  for (int i = 0; i < 4; ++i)
#pragma unroll
    for (int j = 0; j < 4; ++j) acc[i][j] = (float4_t){0.f, 0.f, 0.f, 0.f};

  for (int kc = 0; kc < 8; ++kc) {
    __syncthreads();
#pragma unroll
    for (int i = 0; i < 4; ++i) {
      const int r = i * 32 + (tid >> 3);
      const int g = tid & 7;
      const int p = g ^ (r & 7);
      uint4_t va = *(const uint4_t*)(A + (size_t)(bm * 128 + r) * 512 + kc * 64 + g * 8);
      *(uint4_t*)&lA[r * 64 + p * 8] = va;
      uint4_t vb = *(const uint4_t*)(Bw + (size_t)(bn * 128 + r) * 512 + kc * 64 + g * 8);
      *(uint4_t*)&lB[r * 64 + p * 8] = vb;
    }
    __syncthreads();
#pragma unroll
    for (int ks = 0; ks < 2; ++ks) {
      short8 af[4], bf[4];
#pragma unroll
      for (int i = 0; i < 4; ++i) {
        const int m = mq * 64 + i * 16 + (lane & 15);
        const int blkm = ((lane >> 4) + 4 * ks) ^ (m & 7);
        af[i] = *(const short8*)&lA[m * 64 + blkm * 8];
        const int n = nq * 64 + i * 16 + (lane & 15);
        const int blkn = ((lane >> 4) + 4 * ks) ^ (n & 7);
        bf[i] = *(const short8*)&lB[n * 64 + blkn * 8];
      }
#pragma unroll
      for (int i = 0; i < 4; ++i)
#pragma unroll
        for (int j = 0; j < 4; ++j)
          acc[i][j] = __builtin_amdgcn_mfma_f32_16x16x32_bf16(af[i], bf[j], acc[i][j], 0, 0, 0);
    }
  }
  float biasj[4];
#pragma unroll
  for (int j = 0; j < 4; ++j) {
    const int n = bn * 128 + nq * 64 + j * 16 + (lane & 15);   // 0..4095
    biasj[j] = half ? (bih_b[n] + bhh_b[n]) : (bih_f[n] + bhh_f[n]);
  }
#pragma unroll
  for (int i = 0; i < 4; ++i) {
    const int mt = bm * 8 + mq * 4 + i;          // 0..127
#pragma unroll
    for (int j = 0; j < 4; ++j) {
      const int nt = bn * 8 + nq * 4 + j;        // 0..255
      ushort4_t o;
      o.x = f2bf(acc[i][j].x + biasj[j]);
      o.y = f2bf(acc[i][j].y + biasj[j]);
      o.z = f2bf(acc[i][j].z + biasj[j]);
      o.w = f2bf(acc[i][j].w + biasj[j]);
      *(ushort4_t*)(xp + (size_t)half * 8388608 + ((size_t)mt * 256 + nt) * 256 + lane * 4) = o;
    }
  }
}

// ---------------- K3: cooperative 32-step LSTM chunk (both dirs) ----------------
// 128 WGs x 256 thr, persistent for the chunk. WG = (dir = bid>>6, cgi = bid&63 ->
// h-cols [cgi*16, cgi*16+16)). 4 waves = 4 gates; wave tile [64 b x 16 cols], K=1024.
// Whh slice (64 rows x 1024, 128 KB) lives in LDS for the whole chunk; c in registers;
// grid.sync() between time steps replaces kernel-launch barriers.
__global__ __launch_bounds__(256)
void k_steps32(const unsigned short* __restrict__ xp,      // [2][128 mt][256 nt][256]
               const unsigned short* __restrict__ whh_b,   // [2][4096][1024]
               unsigned short* __restrict__ h_buf,         // [2 dir][2 par][64][1024] bf16
               float* __restrict__ c_state,                // [2 dir][64][1024] fp32
               float* __restrict__ out,                    // [64][512][1024] fp32
               int s0) {
  __shared__ __align__(16) unsigned short wS[64 * 1024];   // 128 KB Whh slice
  __shared__ __align__(16) float sgbuf[4096];              // 16 KB: h-chunk / gate-exchange
  unsigned short* hS = (unsigned short*)sgbuf;
  float* gbuf = sgbuf;

  const int tid = threadIdx.x;
  const int lane = tid & 63;
  const int gt = tid >> 6;            // wave = gate (i,f,g,o)
  const int dir = blockIdx.x >> 6;
  const int cgi = blockIdx.x & 63;

  // ---- preload Whh rows {g*1024 + cgi*16 + r} into LDS, XOR-swizzled per 32-unit group
  {
    const unsigned short* wbase = whh_b + (size_t)dir * 4194304;
#pragma unroll
    for (int g = 0; g < 4; ++g) {
      const unsigned short* gb = wbase + (size_t)(g * 1024 + cgi * 16) * 1024;
#pragma unroll
      for (int i = 0; i < 8; ++i) {
        const int uf = i * 256 + tid;           // 0..2047 (16 rows x 128 units)
        const int r = uf >> 7;
        const int u = uf & 127;
        uint4_t v = *(const uint4_t*)(gb + (size_t)r * 1024 + u * 8);
        const int lr = g * 16 + r;              // LDS row 0..63
        const int phys = (u & 96) | ((u & 31) ^ (lr & 31));
        *(uint4_t*)&wS[(lr * 128 + phys) * 8] = v;
      }
    }
  }

  // ---- c-state in registers for the whole chunk (fixed thread->(b,col) map)
  const int eb = tid >> 2;            // batch 0..63
  const int ecb = (tid & 3) * 4;      // col offset within 16
  float* cp = c_state + (size_t)dir * 65536 + (size_t)eb * 1024 + cgi * 16 + ecb;
  float4_t creg = *(float4_t*)cp;

  cg::grid_group grid = cg::this_grid();
  __syncthreads();                    // wS ready

  const int sr = tid >> 2;            // stage row (batch) 0..63
  const int sg = tid & 3;
  const int mrow = lane & 15;
  const int ntl = gt * 64 + cgi;

  for (int sl = 0; sl < TC; ++sl) {
    const int s = s0 + sl;
    const int t = dir ? (511 - s) : s;
    const int mtlbase = (dir ? (31 - sl) : sl) * 4;

    // ---- xp accumulator init (C-fragment tiles, coalesced 8B/lane)
    float4_t acc[4];
#pragma unroll
    for (int mt = 0; mt < 4; ++mt) {
      ushort4_t xpv = *(const ushort4_t*)(xp + (size_t)dir * 8388608 +
                                          ((size_t)(mtlbase + mt) * 256 + ntl) * 256 + lane * 4);
      acc[mt] = (float4_t){bf2f(xpv.x), bf2f(xpv.y), bf2f(xpv.z), bf2f(xpv.w)};
    }

    const unsigned short* hbase = h_buf + (size_t)(dir * 2 + ((s + 1) & 1)) * 65536;

    for (int kc = 0; kc < 8; ++kc) {
      // fetch h chunk [64 b x 128 k] to regs (global, broadcast across WGs)
      uint4_t hv[4];
#pragma unroll
      for (int i = 0; i < 4; ++i) {
        hv[i] = *(const uint4_t*)(hbase + (size_t)sr * 1024 + kc * 128 + (sg + 4 * i) * 8);
      }
      if (kc) __syncthreads();        // prior chunk's frag reads done
#pragma unroll
      for (int i = 0; i < 4; ++i) {
        const int g = sg + 4 * i;
        *(uint4_t*)&hS[(sr * 16 + (g ^ (sr & 15))) * 8] = hv[i];
      }
      __syncthreads();
#pragma unroll
      for (int ks = 0; ks < 4; ++ks) {
        const int lrB = gt * 16 + mrow;
        const int u = kc * 16 + ks * 4 + (lane >> 4);
        const int physB = (u & 96) | ((u & 31) ^ (lrB & 31));
        short8 bfr = *(const short8*)&wS[(lrB * 128 + physB) * 8];
#pragma unroll
        for (int mt = 0; mt < 4; ++mt) {
          const int m = mt * 16 + mrow;
          const int ua = ks * 4 + (lane >> 4);
          short8 a = *(const short8*)&hS[(m * 16 + (ua ^ (m & 15))) * 8];
          acc[mt] = __builtin_amdgcn_mfma_f32_16x16x32_bf16(a, bfr, acc[mt], 0, 0, 0);
        }
      }
    }

    __syncthreads();                  // hS MFMA reads done before gbuf overwrite (alias!)

    // ---- activations -> gbuf [4 gt][64 b][16 col]
#pragma unroll
    for (int mt = 0; mt < 4; ++mt) {
#pragma unroll
      for (int r = 0; r < 4; ++r) {
        float v = acc[mt][r];
        v = (gt == 2) ? tanhf_(v) : sigmoidf_(v);
        gbuf[gt * 1024 + (mt * 16 + (lane >> 4) * 4 + r) * 16 + mrow] = v;
      }
    }
    __syncthreads();

    // ---- elementwise: thread owns (b = tid>>2, 4 cols at (tid&3)*4)
    {
      float4_t ig = *(float4_t*)&gbuf[eb * 16 + ecb];
      float4_t fg = *(float4_t*)&gbuf[1024 + eb * 16 + ecb];
      float4_t gg = *(float4_t*)&gbuf[2048 + eb * 16 + ecb];
      float4_t og = *(float4_t*)&gbuf[3072 + eb * 16 + ecb];
      creg.x = fg.x * creg.x + ig.x * gg.x;
      creg.y = fg.y * creg.y + ig.y * gg.y;
      creg.z = fg.z * creg.z + ig.z * gg.z;
      creg.w = fg.w * creg.w + ig.w * gg.w;
      float4_t hvv;
      hvv.x = og.x * tanhf_(creg.x);
      hvv.y = og.y * tanhf_(creg.y);
      hvv.z = og.z * tanhf_(creg.z);
      hvv.w = og.w * tanhf_(creg.w);
      ushort4_t hb;
      hb.x = f2bf(hvv.x); hb.y = f2bf(hvv.y); hb.z = f2bf(hvv.z); hb.w = f2bf(hvv.w);
      *(ushort4_t*)(h_buf + (size_t)(dir * 2 + (s & 1)) * 65536 +
                    (size_t)eb * 1024 + cgi * 16 + ecb) = hb;
      // output merge: earlier-step dir plain-stores, later one RMWs (ordered by grid syncs)
      float* op = out + ((size_t)eb * 512 + t) * 1024 + cgi * 16 + ecb;
      const bool first = (dir == 0) == (t < 256);
      if (first) {
        *(float4_t*)op = hvv;
      } else {
        float4_t o = *(float4_t*)op;
        o.x += hvv.x; o.y += hvv.y; o.z += hvv.z; o.w += hvv.w;
        *(float4_t*)op = o;
      }
    }
    if (sl < TC - 1) grid.sync();     // h(s) visible device-wide before step s+1
  }
  *(float4_t*)cp = creg;              // persist c for next chunk
}

extern "C" void kernel_launch(void* const* d_in, const int* in_sizes, int n_in,
                              void* d_out, int out_size, void* d_ws, size_t ws_size,
                              hipStream_t stream) {
  const int*   src  = (const int*)d_in[0];
  const float* emb  = (const float*)d_in[1];
  const float* WihF = (const float*)d_in[2];
  const float* WhhF = (const float*)d_in[3];
  const float* bihF = (const float*)d_in[4];
  const float* bhhF = (const float*)d_in[5];
  const float* WihB = (const float*)d_in[6];
  const float* WhhB = (const float*)d_in[7];
  const float* bihB = (const float*)d_in[8];
  const float* bhhB = (const float*)d_in[9];
  float* out = (float*)d_out;
  char* ws = (char*)d_ws;

  // ws layout (total ~61 MB)
  unsigned short* wih_b   = (unsigned short*)(ws);                    //  8 MB
  unsigned short* whh_b   = (unsigned short*)(ws + 8388608ull);       // 16 MB
  unsigned short* embed_c = (unsigned short*)(ws + 25165824ull);      //  4 MB
  unsigned short* xp      = (unsigned short*)(ws + 29360128ull);      // 32 MB
  unsigned short* hbuf    = (unsigned short*)(ws + 62914560ull);      // 512 KB
  float*          cstate  = (float*)         (ws + 63438848ull);      // 512 KB

  hipMemsetAsync(hbuf, 0, 1048576ull, stream);                        // h ping-pong + c
  k_cvt2<<<2048, 256, 0, stream>>>(WihF, WihB, wih_b, 4096u * 512u);
  k_cvt2<<<4096, 256, 0, stream>>>(WhhF, WhhB, whh_b, 4096u * 1024u);

  for (int ch = 0; ch < NCHUNK; ++ch) {
    const int tF0 = ch * TC;
    const int tB0 = 512 - TC - ch * TC;
    k_embed_c<<<1024, 256, 0, stream>>>(src, emb, embed_c, tF0 * 64, tB0 * 64);
    k_xproj<<<1024, 256, 0, stream>>>(embed_c, wih_b, bihF, bhhF, bihB, bhhB, xp);
    int s0 = ch * TC;
    void* args[] = {(void*)&xp, (void*)&whh_b, (void*)&hbuf, (void*)&cstate,
                    (void*)&out, (void*)&s0};
    hipLaunchCooperativeKernel(k_steps32, dim3(128), dim3(256), args, 0u, stream);
  }
}

// Round 2
// 5869.325 us; speedup vs baseline: 2.1078x; 2.1078x over previous
//
#include <hip/hip_runtime.h>

#define TC 32          // time steps per chunk
#define NCHUNK 16

typedef __attribute__((ext_vector_type(8))) short short8;
typedef __attribute__((ext_vector_type(4))) float float4_t;
typedef __attribute__((ext_vector_type(4))) unsigned int uint4_t;
typedef __attribute__((ext_vector_type(4))) unsigned short ushort4_t;

__device__ inline unsigned short f2bf(float f) {
  union { float f; unsigned u; } v; v.f = f;
  return (unsigned short)((v.u + 0x7fffu + ((v.u >> 16) & 1u)) >> 16);
}
__device__ inline float bf2f(unsigned short b) {
  union { unsigned u; float f; } v; v.u = ((unsigned)b) << 16;
  return v.f;
}
__device__ inline float sigmoidf_(float x) { return 1.f / (1.f + __expf(-x)); }
__device__ inline float tanhf_(float x) {
  float e = __expf(-2.f * fabsf(x));
  float t = (1.f - e) / (1.f + e);
  return x < 0.f ? -t : t;
}

// ---- device-scope (cross-XCD coherent) memory helpers: sc1 = agent scope on gfx950
__device__ inline unsigned ld_u32_dev(const unsigned* a) {
  unsigned v;
  asm volatile("global_load_dword %0, %1, off sc1\n\t"
               "s_waitcnt vmcnt(0)"
               : "=v"(v) : "v"(a) : "memory");
  return v;
}
__device__ inline float4_t ld16_dev(const void* a) {
  float4_t v;
  asm volatile("global_load_dwordx4 %0, %1, off sc1\n\t"
               "s_waitcnt vmcnt(0)"
               : "=v"(v) : "v"(a) : "memory");
  return v;
}
__device__ inline void st8_dev(void* a, ushort4_t v) {
  asm volatile("global_store_dwordx2 %0, %1, off sc1" :: "v"(a), "v"(v) : "memory");
}
__device__ inline void st16_dev(void* a, float4_t v) {
  asm volatile("global_store_dwordx4 %0, %1, off sc1" :: "v"(a), "v"(v) : "memory");
}

// ---------------- K0: fp32 -> bf16 convert, two sources concatenated ----------------
__global__ __launch_bounds__(256)
void k_cvt2(const float* __restrict__ a, const float* __restrict__ b,
            unsigned short* __restrict__ o, unsigned halfElems) {
  const size_t i = ((size_t)blockIdx.x * 256 + threadIdx.x) * 8;
  const float* s = (i < (size_t)halfElems) ? (a + i) : (b + (i - halfElems));
  float4_t x = *(const float4_t*)s;
  float4_t y = *(const float4_t*)(s + 4);
  short8 v;
  v[0]=(short)f2bf(x.x); v[1]=(short)f2bf(x.y); v[2]=(short)f2bf(x.z); v[3]=(short)f2bf(x.w);
  v[4]=(short)f2bf(y.x); v[5]=(short)f2bf(y.y); v[6]=(short)f2bf(y.z); v[7]=(short)f2bf(y.w);
  *(short8*)(o + i) = v;
}

// ---------------- K1: embedding gather for one chunk (2 windows x 2048 rows) ----------------
__global__ __launch_bounds__(256)
void k_embed_c(const int* __restrict__ src, const float* __restrict__ emb,
               unsigned short* __restrict__ o, int rowF0, int rowB0) {
  const int wi = blockIdx.x * 4 + (threadIdx.x >> 6);  // 0..4095
  const int lane = threadIdx.x & 63;
  const int half = wi >> 11;
  const int rl = wi & 2047;
  const int row = (half ? rowB0 : rowF0) + rl;
  const int tok = src[row];
  short8 v;
  if (tok == 0) {
    v = (short8){0,0,0,0,0,0,0,0};
  } else {
    const float* ep = emb + (size_t)tok * 512 + lane * 8;
    float4_t a = *(const float4_t*)(ep);
    float4_t b = *(const float4_t*)(ep + 4);
    v[0]=(short)f2bf(a.x); v[1]=(short)f2bf(a.y); v[2]=(short)f2bf(a.z); v[3]=(short)f2bf(a.w);
    v[4]=(short)f2bf(b.x); v[5]=(short)f2bf(b.y); v[6]=(short)f2bf(b.z); v[7]=(short)f2bf(b.w);
  }
  *(short8*)(o + ((size_t)half * 2048 + rl) * 512 + lane * 8) = v;
}

// ---------------- K2: chunk x_proj GEMM: [2048,512] x [4096,512]^T per half ----------------
// xp layout per half: 16x16 tiles, tile (mt,nt) at (mt*256+nt)*256, elem order lane*4+reg
__global__ __launch_bounds__(256, 2)
void k_xproj(const unsigned short* __restrict__ Aall,   // embed_c [2][2048][512]
             const unsigned short* __restrict__ Ball,   // wih_b   [8192][512]
             const float* __restrict__ bih_f, const float* __restrict__ bhh_f,
             const float* __restrict__ bih_b, const float* __restrict__ bhh_b,
             unsigned short* __restrict__ xp) {
  __shared__ __align__(16) unsigned short lA[128 * 64];
  __shared__ __align__(16) unsigned short lB[128 * 64];
  const int tid = threadIdx.x;
  const int lane = tid & 63;
  const int w = tid >> 6;
  const int mq = w & 1, nq = w >> 1;
  const int half = blockIdx.x >> 9;      // 0 = fwd gates, 1 = bwd gates
  const int idx = blockIdx.x & 511;
  const int bm = idx & 15;               // 16 M-blocks (2048 rows)
  const int bn = idx >> 4;               // 32 N-blocks (4096 cols)
  const unsigned short* A  = Aall + (size_t)half * 1048576;
  const unsigned short* Bw = Ball + (size_t)half * 2097152;

  float4_t acc[4][4];
#pragma unroll
  for (int i = 0; i < 4; ++i)
#pragma unroll
    for (int j = 0; j < 4; ++j) acc[i][j] = (float4_t){0.f, 0.f, 0.f, 0.f};

  for (int kc = 0; kc < 8; ++kc) {
    __syncthreads();
#pragma unroll
    for (int i = 0; i < 4; ++i) {
      const int r = i * 32 + (tid >> 3);
      const int g = tid & 7;
      const int p = g ^ (r & 7);
      uint4_t va = *(const uint4_t*)(A + (size_t)(bm * 128 + r) * 512 + kc * 64 + g * 8);
      *(uint4_t*)&lA[r * 64 + p * 8] = va;
      uint4_t vb = *(const uint4_t*)(Bw + (size_t)(bn * 128 + r) * 512 + kc * 64 + g * 8);
      *(uint4_t*)&lB[r * 64 + p * 8] = vb;
    }
    __syncthreads();
#pragma unroll
    for (int ks = 0; ks < 2; ++ks) {
      short8 af[4], bf[4];
#pragma unroll
      for (int i = 0; i < 4; ++i) {
        const int m = mq * 64 + i * 16 + (lane & 15);
        const int blkm = ((lane >> 4) + 4 * ks) ^ (m & 7);
        af[i] = *(const short8*)&lA[m * 64 + blkm * 8];
        const int n = nq * 64 + i * 16 + (lane & 15);
        const int blkn = ((lane >> 4) + 4 * ks) ^ (n & 7);
        bf[i] = *(const short8*)&lB[n * 64 + blkn * 8];
      }
#pragma unroll
      for (int i = 0; i < 4; ++i)
#pragma unroll
        for (int j = 0; j < 4; ++j)
          acc[i][j] = __builtin_amdgcn_mfma_f32_16x16x32_bf16(af[i], bf[j], acc[i][j], 0, 0, 0);
    }
  }
  float biasj[4];
#pragma unroll
  for (int j = 0; j < 4; ++j) {
    const int n = bn * 128 + nq * 64 + j * 16 + (lane & 15);   // 0..4095
    biasj[j] = half ? (bih_b[n] + bhh_b[n]) : (bih_f[n] + bhh_f[n]);
  }
#pragma unroll
  for (int i = 0; i < 4; ++i) {
    const int mt = bm * 8 + mq * 4 + i;          // 0..127
#pragma unroll
    for (int j = 0; j < 4; ++j) {
      const int nt = bn * 8 + nq * 4 + j;        // 0..255
      ushort4_t o;
      o.x = f2bf(acc[i][j].x + biasj[j]);
      o.y = f2bf(acc[i][j].y + biasj[j]);
      o.z = f2bf(acc[i][j].z + biasj[j]);
      o.w = f2bf(acc[i][j].w + biasj[j]);
      *(ushort4_t*)(xp + (size_t)half * 8388608 + ((size_t)mt * 256 + nt) * 256 + lane * 4) = o;
    }
  }
}

// ---------------- K3: persistent 32-step LSTM chunk (both dirs) ----------------
// 128 WGs x 256 thr. Custom LLC barrier (atomicAdd + sc1 poll) replaces cg::grid.sync.
// All cross-step global traffic (h, out merge) is sc1 device-coherent; weights in LDS;
// c in registers. Depth-2 pipelined h-fetch with counted vmcnt waits.

#define H_ISSUE(KC, D0, D1, D2, D3) do {                                   \
  const unsigned short* ha_ = hbase + (size_t)sr * 1024 + (KC) * 128 + sg * 8; \
  asm volatile("global_load_dwordx4 %0, %4, off sc1\n\t"                   \
               "global_load_dwordx4 %1, %4, off offset:64 sc1\n\t"         \
               "global_load_dwordx4 %2, %4, off offset:128 sc1\n\t"        \
               "global_load_dwordx4 %3, %4, off offset:192 sc1"            \
               : "=&v"(D0), "=&v"(D1), "=&v"(D2), "=&v"(D3)                \
               : "v"(ha_) : "memory");                                     \
} while (0)

#define H_WAIT(N) asm volatile("s_waitcnt vmcnt(" #N ")" ::: "memory")

#define H_STAGE(D0, D1, D2, D3) do {                                       \
  *(uint4_t*)&hS[(sr * 16 + ((sg + 0) ^ (sr & 15))) * 8] = D0;             \
  *(uint4_t*)&hS[(sr * 16 + ((sg + 4) ^ (sr & 15))) * 8] = D1;             \
  *(uint4_t*)&hS[(sr * 16 + ((sg + 8) ^ (sr & 15))) * 8] = D2;             \
  *(uint4_t*)&hS[(sr * 16 + ((sg + 12) ^ (sr & 15))) * 8] = D3;            \
} while (0)

#define XQ_LOAD(SLX) do {                                                  \
  const int mtl_ = (dir ? (31 - (SLX)) : (SLX)) * 4;                       \
  const unsigned short* xb_ = xp + (size_t)dir * 8388608 +                 \
      ((size_t)mtl_ * 256 + ntl) * 256 + lane * 4;                         \
  xq0 = *(const ushort4_t*)(xb_);                                          \
  xq1 = *(const ushort4_t*)(xb_ + 65536);                                  \
  xq2 = *(const ushort4_t*)(xb_ + 131072);                                 \
  xq3 = *(const ushort4_t*)(xb_ + 196608);                                 \
} while (0)

__global__ __launch_bounds__(256)
void k_steps32(const unsigned short* __restrict__ xp,      // [2][128 mt][256 nt][256]
               const unsigned short* __restrict__ whh_b,   // [2][4096][1024]
               unsigned short* __restrict__ h_buf,         // [2 dir][2 par][64][1024] bf16
               float* __restrict__ c_state,                // [2 dir][64][1024] fp32
               float* __restrict__ out,                    // [64][512][1024] fp32
               unsigned* __restrict__ bar,                 // monotonic barrier counter
               int s0, int bar_base) {
  __shared__ __align__(16) unsigned short wS[64 * 1024];   // 128 KB Whh slice
  __shared__ __align__(16) float sgbuf[4096];              // 16 KB: h-chunk / gate-exchange
  unsigned short* hS = (unsigned short*)sgbuf;
  float* gbuf = sgbuf;

  const int tid = threadIdx.x;
  const int lane = tid & 63;
  const int gt = tid >> 6;            // wave = gate (i,f,g,o)
  const int dir = blockIdx.x >> 6;
  const int cgi = blockIdx.x & 63;

  // ---- preload Whh rows {g*1024 + cgi*16 + r} into LDS, XOR-swizzled per 32-unit group
  {
    const unsigned short* wbase = whh_b + (size_t)dir * 4194304;
#pragma unroll
    for (int g = 0; g < 4; ++g) {
      const unsigned short* gb = wbase + (size_t)(g * 1024 + cgi * 16) * 1024;
#pragma unroll
      for (int i = 0; i < 8; ++i) {
        const int uf = i * 256 + tid;           // 0..2047 (16 rows x 128 units)
        const int r = uf >> 7;
        const int u = uf & 127;
        uint4_t v = *(const uint4_t*)(gb + (size_t)r * 1024 + u * 8);
        const int lr = g * 16 + r;              // LDS row 0..63
        const int phys = (u & 96) | ((u & 31) ^ (lr & 31));
        *(uint4_t*)&wS[(lr * 128 + phys) * 8] = v;
      }
    }
  }

  // ---- c-state in registers for the whole chunk (fixed thread->(b,col) map)
  const int eb = tid >> 2;            // batch 0..63
  const int ecb = (tid & 3) * 4;      // col offset within 16
  float* cp = c_state + (size_t)dir * 65536 + (size_t)eb * 1024 + cgi * 16 + ecb;
  float4_t creg = *(float4_t*)cp;

  __syncthreads();                    // wS ready

  const int sr = tid >> 2;            // stage row (batch) 0..63
  const int sg = tid & 3;
  const int mrow = lane & 15;
  const int ntl = gt * 64 + cgi;

  ushort4_t xq0, xq1, xq2, xq3;
  XQ_LOAD(0);

  for (int sl = 0; sl < TC; ++sl) {
    const int s = s0 + sl;
    const int t = dir ? (511 - s) : s;
    const unsigned short* hbase = h_buf + (size_t)(dir * 2 + ((s + 1) & 1)) * 65536;

    // ---- barrier wait: all WGs finished step sl-1 (h(s-1) at LLC)
    if (sl) {
      const unsigned target = 128u * (unsigned)(bar_base + sl);
      if (tid == 0) {
        while (ld_u32_dev(bar) < target) __builtin_amdgcn_s_sleep(1);
      }
      __syncthreads();
    }

    // ---- xp accumulator init from prefetched regs
    float4_t acc[4];
    acc[0] = (float4_t){bf2f(xq0.x), bf2f(xq0.y), bf2f(xq0.z), bf2f(xq0.w)};
    acc[1] = (float4_t){bf2f(xq1.x), bf2f(xq1.y), bf2f(xq1.z), bf2f(xq1.w)};
    acc[2] = (float4_t){bf2f(xq2.x), bf2f(xq2.y), bf2f(xq2.z), bf2f(xq2.w)};
    acc[3] = (float4_t){bf2f(xq3.x), bf2f(xq3.y), bf2f(xq3.z), bf2f(xq3.w)};
    __builtin_amdgcn_sched_barrier(0);  // keep xq waitcnt above the hidden asm loads

    // ---- depth-2 pipelined h fetch + MFMA
    uint4_t ha0, ha1, ha2, ha3, hb0, hb1, hb2, hb3;
    H_ISSUE(0, ha0, ha1, ha2, ha3);
    H_ISSUE(1, hb0, hb1, hb2, hb3);

#pragma unroll
    for (int kc = 0; kc < 8; ++kc) {
      if (kc) __syncthreads();        // prior chunk's frag reads done
      if (kc < 7) { H_WAIT(4); } else { H_WAIT(0); }
      if (kc & 1) {
        H_STAGE(hb0, hb1, hb2, hb3);
        if (kc < 6) H_ISSUE(kc + 2, hb0, hb1, hb2, hb3);
      } else {
        H_STAGE(ha0, ha1, ha2, ha3);
        if (kc < 6) H_ISSUE(kc + 2, ha0, ha1, ha2, ha3);
      }
      __syncthreads();
#pragma unroll
      for (int ks = 0; ks < 4; ++ks) {
        const int lrB = gt * 16 + mrow;
        const int u = kc * 16 + ks * 4 + (lane >> 4);
        const int physB = (u & 96) | ((u & 31) ^ (lrB & 31));
        short8 bfr = *(const short8*)&wS[(lrB * 128 + physB) * 8];
#pragma unroll
        for (int mt = 0; mt < 4; ++mt) {
          const int m = mt * 16 + mrow;
          const int ua = ks * 4 + (lane >> 4);
          short8 a = *(const short8*)&hS[(m * 16 + (ua ^ (m & 15))) * 8];
          acc[mt] = __builtin_amdgcn_mfma_f32_16x16x32_bf16(a, bfr, acc[mt], 0, 0, 0);
        }
      }
    }

    __syncthreads();                  // hS MFMA reads done before gbuf overwrite (alias!)

    // ---- activations -> gbuf [4 gt][64 b][16 col]
#pragma unroll
    for (int mt = 0; mt < 4; ++mt) {
#pragma unroll
      for (int r = 0; r < 4; ++r) {
        float v = acc[mt][r];
        v = (gt == 2) ? tanhf_(v) : sigmoidf_(v);
        gbuf[gt * 1024 + (mt * 16 + (lane >> 4) * 4 + r) * 16 + mrow] = v;
      }
    }
    __syncthreads();

    // ---- elementwise: thread owns (b = tid>>2, 4 cols at (tid&3)*4)
    {
      float4_t ig = *(float4_t*)&gbuf[eb * 16 + ecb];
      float4_t fg = *(float4_t*)&gbuf[1024 + eb * 16 + ecb];
      float4_t gg = *(float4_t*)&gbuf[2048 + eb * 16 + ecb];
      float4_t og = *(float4_t*)&gbuf[3072 + eb * 16 + ecb];
      creg.x = fg.x * creg.x + ig.x * gg.x;
      creg.y = fg.y * creg.y + ig.y * gg.y;
      creg.z = fg.z * creg.z + ig.z * gg.z;
      creg.w = fg.w * creg.w + ig.w * gg.w;
      float4_t hvv;
      hvv.x = og.x * tanhf_(creg.x);
      hvv.y = og.y * tanhf_(creg.y);
      hvv.z = og.z * tanhf_(creg.z);
      hvv.w = og.w * tanhf_(creg.w);
      ushort4_t hbp;
      hbp.x = f2bf(hvv.x); hbp.y = f2bf(hvv.y); hbp.z = f2bf(hvv.z); hbp.w = f2bf(hvv.w);
      st8_dev(h_buf + (size_t)(dir * 2 + (s & 1)) * 65536 +
              (size_t)eb * 1024 + cgi * 16 + ecb, hbp);
      // output merge: earlier-step dir sc1-stores, later one RMW-loads sc1 (barrier-ordered)
      float* op = out + ((size_t)eb * 512 + t) * 1024 + cgi * 16 + ecb;
      const bool first = (dir == 0) == (t < 256);
      if (first) {
        st16_dev(op, hvv);
      } else {
        float4_t o = ld16_dev(op);
        o.x += hvv.x; o.y += hvv.y; o.z += hvv.z; o.w += hvv.w;
        *(float4_t*)op = o;
      }
    }

    // ---- barrier arrive, then prefetch next step's xp while others finish
    if (sl < TC - 1) {
      asm volatile("s_waitcnt vmcnt(0)" ::: "memory");  // my sc1 stores at LLC
      __syncthreads();                                  // all 4 waves drained
      if (tid == 0) atomicAdd(bar, 1u);                 // device-scope release
      XQ_LOAD(sl + 1);
    }
  }
  *(float4_t*)cp = creg;              // persist c for next chunk
}

extern "C" void kernel_launch(void* const* d_in, const int* in_sizes, int n_in,
                              void* d_out, int out_size, void* d_ws, size_t ws_size,
                              hipStream_t stream) {
  const int*   src  = (const int*)d_in[0];
  const float* emb  = (const float*)d_in[1];
  const float* WihF = (const float*)d_in[2];
  const float* WhhF = (const float*)d_in[3];
  const float* bihF = (const float*)d_in[4];
  const float* bhhF = (const float*)d_in[5];
  const float* WihB = (const float*)d_in[6];
  const float* WhhB = (const float*)d_in[7];
  const float* bihB = (const float*)d_in[8];
  const float* bhhB = (const float*)d_in[9];
  float* out = (float*)d_out;
  char* ws = (char*)d_ws;

  // ws layout (total ~61 MB)
  unsigned short* wih_b   = (unsigned short*)(ws);                    //  8 MB
  unsigned short* whh_b   = (unsigned short*)(ws + 8388608ull);       // 16 MB
  unsigned short* embed_c = (unsigned short*)(ws + 25165824ull);      //  4 MB
  unsigned short* xp      = (unsigned short*)(ws + 29360128ull);      // 32 MB
  unsigned short* hbuf    = (unsigned short*)(ws + 62914560ull);      // 512 KB
  float*          cstate  = (float*)         (ws + 63438848ull);      // 512 KB
  unsigned*       bar     = (unsigned*)      (ws + 63963136ull);      // barrier counter

  hipMemsetAsync(hbuf, 0, 1048576ull + 256ull, stream);               // h + c + barrier
  k_cvt2<<<2048, 256, 0, stream>>>(WihF, WihB, wih_b, 4096u * 512u);
  k_cvt2<<<4096, 256, 0, stream>>>(WhhF, WhhB, whh_b, 4096u * 1024u);

  for (int ch = 0; ch < NCHUNK; ++ch) {
    const int tF0 = ch * TC;
    const int tB0 = 512 - TC - ch * TC;
    k_embed_c<<<1024, 256, 0, stream>>>(src, emb, embed_c, tF0 * 64, tB0 * 64);
    k_xproj<<<1024, 256, 0, stream>>>(embed_c, wih_b, bihF, bhhF, bihB, bhhB, xp);
    int s0 = ch * TC;
    int bar_base = ch * (TC - 1);
    void* args[] = {(void*)&xp, (void*)&whh_b, (void*)&hbuf, (void*)&cstate,
                    (void*)&out, (void*)&bar, (void*)&s0, (void*)&bar_base};
    hipLaunchCooperativeKernel(k_steps32, dim3(128), dim3(256), args, 0u, stream);
  }
}